// Round 15
// baseline (225.749 us; speedup 1.0000x reference)
//
#include <hip/hip_runtime.h>
#include <hip/hip_fp8.h>

// CausalConv3dFP8 round 15: break the per-tier "ds_read -> lgkmcnt(0) -> MFMA"
// serialization. B-fragments (and A) software-pipelined 1 tier deep through
// register parity buffers; NO inline-asm waits / sched_barriers in the loop —
// compiler emits counted lgkmcnt, tier-t wait covers reads issued ~600 cyc ago.
// r9 lean base otherwise: acc 64 AGPR, split-half LDS, kd-skip, XCD swizzle.
// xq layout: [b][d4][hp194][ci32 grp 4][wp322][32B]
// wpk layout: [tap27][cc2][cq4][lane64][32B]

using f32x16 = __attribute__((ext_vector_type(16))) float;
using i32x8 = __attribute__((ext_vector_type(8))) int;
using i32x4 = __attribute__((ext_vector_type(4))) int;
typedef long long i64;
struct alignas(16) L2v { i64 x, y; };

namespace {
constexpr int Cc = 128, Dd = 4, Hh = 192, Ww = 320;
constexpr int HP = 194, WP = 322;
constexpr int NTAP = 27;
constexpr size_t PLANE = (size_t)4 * WP * 32;               // 41,216 B per (b,d,h) row-plane
constexpr size_t XQ_BYTES = (size_t)2 * Dd * HP * PLANE;    // 63,967,232
constexpr int ZA = 8 * 2 * 2576;
constexpr int ZB = 8 * 192 * 32;
constexpr int GSTR = WP * 32;                               // 10,304 B per ci32-group
constexpr int HB = 1056;                                    // 66*16 half-plane stride
constexpr int KDSTR = 9 * 2 * 4 * 64 * 32;                  // 147,456 B per kd in wpk
constexpr int NQX = 5 * 192 * 8;
constexpr int NZP = (ZA + ZB + 255) / 256;
constexpr int NWP = (Cc * Cc * NTAP + 255) / 256;
}

__global__ __launch_bounds__(256) void prep_kernel(const float* __restrict__ x,
                                                   const float* __restrict__ w,
                                                   unsigned char* __restrict__ xq,
                                                   unsigned char* __restrict__ wpk) {
  const int id = blockIdx.x;
  const int tid = threadIdx.x;
  if (id < NQX) {
    __shared__ unsigned char lt[64 * 136];
    const int wx = id % 5;
    const int h = (id / 5) % 192;
    const int bd = id / 960;
    const int b = bd >> 2, d = bd & 3;
    const int w0 = wx * 64;
    const int wl = tid & 63, cig = tid >> 6;
    const size_t cstr = (size_t)Dd * Hh * Ww;
    const float* xp = x + (((size_t)b * Cc * Dd + d) * Hh + h) * Ww + w0 + wl;
    #pragma unroll 4
    for (int i = 0; i < 32; ++i) {
      int ci = cig * 32 + i;
      __hip_fp8_e4m3 q(xp[ci * cstr]);
      lt[wl * 136 + ci] = q.__x;
    }
    __syncthreads();
    unsigned char* plane = xq + ((size_t)(b * Dd + d) * HP + h + 1) * PLANE;
    int g = tid >> 6, ww = tid & 63;
    const unsigned char* src = lt + ww * 136 + g * 32;
    i64 a0 = *(const i64*)(src), a1 = *(const i64*)(src + 8);
    i64 a2 = *(const i64*)(src + 16), a3 = *(const i64*)(src + 24);
    unsigned char* dst = plane + (size_t)g * GSTR + (size_t)(w0 + 1 + ww) * 32;
    *(L2v*)dst = L2v{a0, a1};
    *(L2v*)(dst + 16) = L2v{a2, a3};
  } else if (id < NQX + NZP) {
    int i = (id - NQX) * 256 + tid;
    if (i < ZA) {
      int bd = i / (2 * 2576);
      int r = i - bd * (2 * 2576);
      int hsel = r / 2576, seg = r - hsel * 2576;
      L2v z{0, 0};
      *(L2v*)(xq + ((size_t)bd * HP + (hsel ? 193 : 0)) * PLANE + (size_t)seg * 16) = z;
    } else if (i < ZA + ZB) {
      int j = i - ZA;
      int bd = j / (192 * 32);
      int r = j - bd * (192 * 32);
      int h = r / 32 + 1;
      int t = r & 31;
      int g = t >> 3, s2 = t & 7;
      int wsel = s2 >> 2, part = s2 & 3;
      *(i64*)(xq + ((size_t)bd * HP + h) * PLANE + (size_t)g * GSTR
              + (size_t)(wsel ? 321 : 0) * 32 + part * 8) = 0;
    }
  } else {
    int idx = (id - NQX - NZP) * 256 + tid;
    if (idx < Cc * Cc * NTAP) {
      int tap = idx % NTAP;
      int t = idx / NTAP;
      int ci = t % Cc, co = t / Cc;
      int cc = ci >> 6, cq = co >> 5;
      int lane = (((ci >> 5) & 1) << 5) | (co & 31);
      __hip_fp8_e4m3 q(w[idx]);
      wpk[((((size_t)tap * 2 + cc) * 4 + cq) * 64 + lane) * 32 + (ci & 31)] = q.__x;
    }
  }
}

__global__ __launch_bounds__(256, 3) void conv_mfma(const unsigned char* __restrict__ xq,
                                                    const unsigned char* __restrict__ wpk,
                                                    float* __restrict__ out) {
  __shared__ unsigned char lb[4 * 4 * 2 * HB];     // 33,792 B
  const int tid = threadIdx.x;
  const int lane = tid & 63, wv = tid >> 6;
  const int l31 = lane & 31, chalf = lane >> 5;
  const int hr = wv >> 1, ch = wv & 1;
  const int id = blockIdx.x;
  const int xcd = id & 7, j = id >> 3;
  const int h0l = j / 40, rem = j - h0l * 40;
  const int z = rem / 5, wx = rem - z * 5;
  const int b = z >> 2, dout = z & 3;
  const int h0 = (xcd * 12 + h0l) * 2;
  const int w0 = wx * 64;
  const int kdmin = dout >= 2 ? 0 : 2 - dout;

  const long imgstep = (long)HP * PLANE;
  const long img0 = (long)(b * Dd + dout - 2) * imgstep;
  const unsigned char* vbase = wpk + ch * 4096 + lane * 32;

  const unsigned char* bb[3];
  #pragma unroll
  for (int kw = 0; kw < 3; ++kw)
    bb[kw] = lb + (hr * 4 + chalf) * 2 * HB + (l31 + kw) * 16;

  f32x16 acc[2][2];                                // [ct][nf] = 64 AGPR
  #pragma unroll
  for (int a = 0; a < 2; ++a)
    #pragma unroll
    for (int n = 0; n < 2; ++n)
      #pragma unroll
      for (int r = 0; r < 16; ++r) acc[a][n][r] = 0.f;

  i32x8 bvd[2][2];                                 // [parity][nf]
  i32x8 avd[2][2];                                 // [parity][ct]

#define LOADB(PAR, T)                                                          \
  {                                                                            \
    constexpr int kh_ = (T) / 6, cc_ = ((T) / 3) % 2, kw_ = (T) % 3;           \
    _Pragma("unroll")                                                          \
    for (int nf = 0; nf < 2; ++nf) {                                           \
      const int off_ = (kh_ * 4 + cc_ * 2) * 2 * HB + nf * 512;                \
      i32x4 blo_ = *(const i32x4*)(bb[kw_] + off_);                            \
      i32x4 bhi_ = *(const i32x4*)(bb[kw_] + off_ + HB);                       \
      bvd[PAR][nf] = __builtin_shufflevector(blo_, bhi_, 0, 1, 2, 3, 4, 5, 6, 7); \
    }                                                                          \
  }
#define LOADA(PAR, T)                                                          \
  {                                                                            \
    constexpr int kh_ = (T) / 6, cc_ = ((T) / 3) % 2, kw_ = (T) % 3;           \
    _Pragma("unroll")                                                          \
    for (int ct = 0; ct < 2; ++ct)                                             \
      avd[PAR][ct] = *(const i32x8*)(wkd + (kh_ * 3 + kw_) * 16384             \
                                     + cc_ * 8192 + ct * 2048);                \
  }

  for (int kd = kdmin; kd < 3; ++kd) {
    __syncthreads();
    // ---- stage [hrow4][g4][half2][66w] for this kd (reg-staged) ----
    const unsigned char* img = xq + img0 + (long)kd * imgstep;
    for (int u = tid; u < 1056; u += 256) {
      int w = u % 66, rest = u / 66;
      int g = rest & 3, hrow = rest >> 2;
      const unsigned char* src = img + (size_t)(h0 + hrow) * PLANE
          + (size_t)g * GSTR + (size_t)(w0 + w) * 32;
      L2v lo = *(const L2v*)src;
      L2v hi = *(const L2v*)(src + 16);
      unsigned char* base = lb + (hrow * 4 + g) * 2 * HB + w * 16;
      *(L2v*)(base) = lo;
      *(L2v*)(base + HB) = hi;
    }
    __syncthreads();

    const unsigned char* wkd = vbase + (size_t)kd * KDSTR;
    LOADB(0, 0)
    LOADA(0, 0)
    __builtin_amdgcn_s_setprio(1);
    #pragma unroll
    for (int t = 0; t < 18; ++t) {
      const int p = t & 1, q = p ^ 1;
      // ---- prefetch tier t+1 into the other parity (no fences: compiler
      //      emits counted lgkmcnt; tier-t's reads were issued a tier ago) ----
      switch (t) {                                  // compile-time T for macro
        case 0:  LOADB(1, 1)  LOADA(1, 1)  break;
        case 1:  LOADB(0, 2)  LOADA(0, 2)  break;
        case 2:  LOADB(1, 3)  LOADA(1, 3)  break;
        case 3:  LOADB(0, 4)  LOADA(0, 4)  break;
        case 4:  LOADB(1, 5)  LOADA(1, 5)  break;
        case 5:  LOADB(0, 6)  LOADA(0, 6)  break;
        case 6:  LOADB(1, 7)  LOADA(1, 7)  break;
        case 7:  LOADB(0, 8)  LOADA(0, 8)  break;
        case 8:  LOADB(1, 9)  LOADA(1, 9)  break;
        case 9:  LOADB(0, 10) LOADA(0, 10) break;
        case 10: LOADB(1, 11) LOADA(1, 11) break;
        case 11: LOADB(0, 12) LOADA(0, 12) break;
        case 12: LOADB(1, 13) LOADA(1, 13) break;
        case 13: LOADB(0, 14) LOADA(0, 14) break;
        case 14: LOADB(1, 15) LOADA(1, 15) break;
        case 15: LOADB(0, 16) LOADA(0, 16) break;
        case 16: LOADB(1, 17) LOADA(1, 17) break;
        default: break;
      }
      #pragma unroll
      for (int nf = 0; nf < 2; ++nf)
        #pragma unroll
        for (int ct = 0; ct < 2; ++ct)
          acc[ct][nf] = __builtin_amdgcn_mfma_scale_f32_32x32x64_f8f6f4(
              avd[p][ct], bvd[p][nf], acc[ct][nf], 0, 0, 0, 127, 0, 127);
    }
    __builtin_amdgcn_s_setprio(0);
  }
#undef LOADB
#undef LOADA

  // ---- epilogue: col=l31 -> w, row=(reg&3)+8*(reg>>2)+4*chalf -> cout ----
  #pragma unroll
  for (int ct = 0; ct < 2; ++ct)
    #pragma unroll
    for (int nf = 0; nf < 2; ++nf) {
      int ww = w0 + nf * 32 + l31;
      #pragma unroll
      for (int reg = 0; reg < 16; ++reg) {
        int co = ch * 64 + ct * 32 + (reg & 3) + 8 * (reg >> 2) + 4 * chalf;
        out[(((size_t)b * Cc + co) * Dd + dout) * (size_t)(Hh * Ww)
            + (size_t)(h0 + hr) * Ww + ww] = acc[ct][nf][reg];
      }
    }
}

extern "C" void kernel_launch(void* const* d_in, const int* in_sizes, int n_in,
                              void* d_out, int out_size, void* d_ws, size_t ws_size,
                              hipStream_t stream) {
  const float* x = (const float*)d_in[0];
  const float* w = (const float*)d_in[1];
  unsigned char* xq = (unsigned char*)d_ws;
  unsigned char* wpk = xq + XQ_BYTES;              // 442,368 B
  float* out = (float*)d_out;

  prep_kernel<<<dim3(NQX + NZP + NWP), 256, 0, stream>>>(x, w, xq, wpk);
  conv_mfma<<<dim3(3840), 256, 0, stream>>>(xq, wpk, out);
}